// Round 5
// baseline (336.559 us; speedup 1.0000x reference)
//
#include <hip/hip_runtime.h>
#include <math.h>

// Problem constants (match reference)
#define B_ROWS 2048
#define V_COLS 32000
#define SCALE_D 30.0
#define COS_MARGIN_D 0.35
#define ARC_MARGIN_D 0.5
#define EPS_D 1e-12
#define PI_D 3.14159265358979323846

// exp(SCALE*x) = exp2(x * 30*log2(e)); arg range +/-43.3 -> raw v_exp_f32 ok.
#define LOG2E_X30 43.2808512266689022212f

// native vector type -- __builtin_nontemporal_load rejects HIP's float4 class
typedef float f32x4 __attribute__((ext_vector_type(4)));

#define ROWS_PER_BLOCK 4
#define NBLOCKS (B_ROWS / ROWS_PER_BLOCK)  // 512

// Each block streams a 512 KB slab of 4 consecutive rows (fewer, longer
// DRAM streams than one-block-per-row: 512 streams vs 2048 -> better
// row-buffer locality). Per row: 2 nt float4 loads in flight per thread,
// 8 fp32 accumulators, then wave+LDS reduce and scalar epilogue.
__global__ __launch_bounds__(256) void cosarc_row_kernel(
    const float* __restrict__ preds,
    const int*   __restrict__ labels,
    float*       __restrict__ row_terms)
{
    const int tid = threadIdx.x;
    const int wave = tid >> 6;
    const int lane = tid & 63;
    const int NV4 = V_COLS / 4;  // 8000

    __shared__ double wave_sums[4];

    for (int r = 0; r < ROWS_PER_BLOCK; ++r) {
        const int row = blockIdx.x * ROWS_PER_BLOCK + r;
        const float* rowp = preds + (size_t)row * V_COLS;
        const f32x4* rowp4 = (const f32x4*)rowp;

        float s0 = 0.f, s1 = 0.f, s2 = 0.f, s3 = 0.f;
        float s4 = 0.f, s5 = 0.f, s6 = 0.f, s7 = 0.f;

        int i = tid;
        for (; i + 256 < NV4; i += 512) {
            f32x4 a = __builtin_nontemporal_load(&rowp4[i]);
            f32x4 b = __builtin_nontemporal_load(&rowp4[i + 256]);
            s0 += __builtin_amdgcn_exp2f(a.x * LOG2E_X30);
            s1 += __builtin_amdgcn_exp2f(a.y * LOG2E_X30);
            s2 += __builtin_amdgcn_exp2f(a.z * LOG2E_X30);
            s3 += __builtin_amdgcn_exp2f(a.w * LOG2E_X30);
            s4 += __builtin_amdgcn_exp2f(b.x * LOG2E_X30);
            s5 += __builtin_amdgcn_exp2f(b.y * LOG2E_X30);
            s6 += __builtin_amdgcn_exp2f(b.z * LOG2E_X30);
            s7 += __builtin_amdgcn_exp2f(b.w * LOG2E_X30);
        }
        if (i < NV4) {  // tail
            f32x4 a = __builtin_nontemporal_load(&rowp4[i]);
            s0 += __builtin_amdgcn_exp2f(a.x * LOG2E_X30);
            s1 += __builtin_amdgcn_exp2f(a.y * LOG2E_X30);
            s2 += __builtin_amdgcn_exp2f(a.z * LOG2E_X30);
            s3 += __builtin_amdgcn_exp2f(a.w * LOG2E_X30);
        }
        double sum = (double)(((s0 + s1) + (s2 + s3)) + ((s4 + s5) + (s6 + s7)));

        #pragma unroll
        for (int off = 32; off > 0; off >>= 1)
            sum += __shfl_down(sum, off, 64);

        if (lane == 0) wave_sums[wave] = sum;
        __syncthreads();

        if (tid == 0) {
            double total = wave_sums[0] + wave_sums[1] + wave_sums[2] + wave_sums[3];

            const float tgt_f = rowp[labels[row]];
            const double sum_others =
                total - (double)__builtin_amdgcn_exp2f(tgt_f * LOG2E_X30);

            double t = (double)tgt_f;
            t = fmin(fmax(t, -1.0 + EPS_D), 1.0 - EPS_D);
            double theta = acos(t);
            theta = fmin(fmax(theta, EPS_D), PI_D - EPS_D);
            const double numerator = SCALE_D * (cos(theta + ARC_MARGIN_D) - COS_MARGIN_D);
            const double denominator = exp(numerator) + sum_others;
            row_terms[row] = (float)(numerator - log(denominator));
        }
        __syncthreads();  // protect wave_sums reuse next row
    }
}

// Reduce the 2048 per-row terms to -mean.
__global__ __launch_bounds__(256) void cosarc_reduce_kernel(
    const float* __restrict__ row_terms,
    float*       __restrict__ out)
{
    const int tid = threadIdx.x;
    double s = 0.0;
    for (int i = tid; i < B_ROWS; i += 256)
        s += (double)row_terms[i];

    #pragma unroll
    for (int off = 32; off > 0; off >>= 1)
        s += __shfl_down(s, off, 64);

    __shared__ double wave_sums[4];
    if ((tid & 63) == 0) wave_sums[tid >> 6] = s;
    __syncthreads();

    if (tid == 0) {
        double total = wave_sums[0] + wave_sums[1] + wave_sums[2] + wave_sums[3];
        out[0] = (float)(-(total / (double)B_ROWS));
    }
}

extern "C" void kernel_launch(void* const* d_in, const int* in_sizes, int n_in,
                              void* d_out, int out_size, void* d_ws, size_t ws_size,
                              hipStream_t stream)
{
    const float* preds  = (const float*)d_in[0];
    const int*   labels = (const int*)d_in[1];
    float*       out    = (float*)d_out;
    float*       ws     = (float*)d_ws;   // needs B_ROWS*4 = 8 KB

    cosarc_row_kernel<<<NBLOCKS, 256, 0, stream>>>(preds, labels, ws);
    cosarc_reduce_kernel<<<1, 256, 0, stream>>>(ws, out);
}

// Round 6
// 328.118 us; speedup vs baseline: 1.0257x; 1.0257x over previous
//
#include <hip/hip_runtime.h>
#include <math.h>

// Problem constants (match reference)
#define B_ROWS 2048
#define V_COLS 32000
#define SCALE_D 30.0
#define COS_MARGIN_D 0.35
#define ARC_MARGIN_D 0.5
#define EPS_D 1e-12
#define PI_D 3.14159265358979323846

// exp(SCALE*x) = exp2(x * 30*log2(e)); arg range +/-43.3 -> raw v_exp_f32 ok.
#define LOG2E_X30 43.2808512266689022212f

// native vector type -- __builtin_nontemporal_load rejects HIP's float4 class
typedef float f32x4 __attribute__((ext_vector_type(4)));

// One block per row (2048 blocks = 8 blocks/CU = full 32 waves/CU occupancy;
// R5 showed occupancy dominates stream length for this pattern).
// FOUR nontemporal float4 loads in flight per thread, 16 fp32 accumulators.
__global__ __launch_bounds__(256) void cosarc_row_kernel(
    const float* __restrict__ preds,
    const int*   __restrict__ labels,
    float*       __restrict__ row_terms)
{
    const int row = blockIdx.x;
    const int tid = threadIdx.x;
    const float* rowp = preds + (size_t)row * V_COLS;
    const f32x4* rowp4 = (const f32x4*)rowp;
    const int NV4 = V_COLS / 4;  // 8000

    float s0 = 0.f, s1 = 0.f, s2 = 0.f, s3 = 0.f;
    float s4 = 0.f, s5 = 0.f, s6 = 0.f, s7 = 0.f;
    float s8 = 0.f, s9 = 0.f, sa = 0.f, sb = 0.f;
    float sc = 0.f, sd = 0.f, se = 0.f, sf = 0.f;

    int i = tid;
    for (; i + 768 < NV4; i += 1024) {
        f32x4 a = __builtin_nontemporal_load(&rowp4[i]);
        f32x4 b = __builtin_nontemporal_load(&rowp4[i + 256]);
        f32x4 c = __builtin_nontemporal_load(&rowp4[i + 512]);
        f32x4 d = __builtin_nontemporal_load(&rowp4[i + 768]);
        s0 += __builtin_amdgcn_exp2f(a.x * LOG2E_X30);
        s1 += __builtin_amdgcn_exp2f(a.y * LOG2E_X30);
        s2 += __builtin_amdgcn_exp2f(a.z * LOG2E_X30);
        s3 += __builtin_amdgcn_exp2f(a.w * LOG2E_X30);
        s4 += __builtin_amdgcn_exp2f(b.x * LOG2E_X30);
        s5 += __builtin_amdgcn_exp2f(b.y * LOG2E_X30);
        s6 += __builtin_amdgcn_exp2f(b.z * LOG2E_X30);
        s7 += __builtin_amdgcn_exp2f(b.w * LOG2E_X30);
        s8 += __builtin_amdgcn_exp2f(c.x * LOG2E_X30);
        s9 += __builtin_amdgcn_exp2f(c.y * LOG2E_X30);
        sa += __builtin_amdgcn_exp2f(c.z * LOG2E_X30);
        sb += __builtin_amdgcn_exp2f(c.w * LOG2E_X30);
        sc += __builtin_amdgcn_exp2f(d.x * LOG2E_X30);
        sd += __builtin_amdgcn_exp2f(d.y * LOG2E_X30);
        se += __builtin_amdgcn_exp2f(d.z * LOG2E_X30);
        sf += __builtin_amdgcn_exp2f(d.w * LOG2E_X30);
    }
    for (; i < NV4; i += 256) {  // tail: at most 3 single loads per thread
        f32x4 a = __builtin_nontemporal_load(&rowp4[i]);
        s0 += __builtin_amdgcn_exp2f(a.x * LOG2E_X30);
        s1 += __builtin_amdgcn_exp2f(a.y * LOG2E_X30);
        s2 += __builtin_amdgcn_exp2f(a.z * LOG2E_X30);
        s3 += __builtin_amdgcn_exp2f(a.w * LOG2E_X30);
    }
    double sum = (double)((((s0 + s1) + (s2 + s3)) + ((s4 + s5) + (s6 + s7)))
                        + (((s8 + s9) + (sa + sb)) + ((sc + sd) + (se + sf))));

    // wave(64) shuffle reduction
    #pragma unroll
    for (int off = 32; off > 0; off >>= 1)
        sum += __shfl_down(sum, off, 64);

    __shared__ double wave_sums[4];
    const int wave = tid >> 6;
    const int lane = tid & 63;
    if (lane == 0) wave_sums[wave] = sum;
    __syncthreads();

    if (tid == 0) {
        double total = wave_sums[0] + wave_sums[1] + wave_sums[2] + wave_sums[3];

        const float tgt_f = rowp[labels[row]];
        // subtract the same fp32 exp term that was accumulated for the target
        const double sum_others =
            total - (double)__builtin_amdgcn_exp2f(tgt_f * LOG2E_X30);

        double t = (double)tgt_f;
        t = fmin(fmax(t, -1.0 + EPS_D), 1.0 - EPS_D);
        double theta = acos(t);
        theta = fmin(fmax(theta, EPS_D), PI_D - EPS_D);
        const double numerator = SCALE_D * (cos(theta + ARC_MARGIN_D) - COS_MARGIN_D);
        const double denominator = exp(numerator) + sum_others;
        row_terms[row] = (float)(numerator - log(denominator));
    }
}

// Reduce the 2048 per-row terms to -mean.
__global__ __launch_bounds__(256) void cosarc_reduce_kernel(
    const float* __restrict__ row_terms,
    float*       __restrict__ out)
{
    const int tid = threadIdx.x;
    double s = 0.0;
    for (int i = tid; i < B_ROWS; i += 256)
        s += (double)row_terms[i];

    #pragma unroll
    for (int off = 32; off > 0; off >>= 1)
        s += __shfl_down(s, off, 64);

    __shared__ double wave_sums[4];
    if ((tid & 63) == 0) wave_sums[tid >> 6] = s;
    __syncthreads();

    if (tid == 0) {
        double total = wave_sums[0] + wave_sums[1] + wave_sums[2] + wave_sums[3];
        out[0] = (float)(-(total / (double)B_ROWS));
    }
}

extern "C" void kernel_launch(void* const* d_in, const int* in_sizes, int n_in,
                              void* d_out, int out_size, void* d_ws, size_t ws_size,
                              hipStream_t stream)
{
    const float* preds  = (const float*)d_in[0];
    const int*   labels = (const int*)d_in[1];
    float*       out    = (float*)d_out;
    float*       ws     = (float*)d_ws;   // needs B_ROWS*4 = 8 KB

    cosarc_row_kernel<<<B_ROWS, 256, 0, stream>>>(preds, labels, ws);
    cosarc_reduce_kernel<<<1, 256, 0, stream>>>(ws, out);
}